// Round 1
// 508.100 us; speedup vs baseline: 1.3466x; 1.3466x over previous
//
#include <hip/hip_runtime.h>
#include <math.h>

// WindowAttention: B=2048, C=256, H=8, d_k=32, wh=ww=7 -> L=49, nW=64.
// Reference reassigns v = k. Outputs: score (2048*256*49) then attn
// (2048*8*49*49), fp32, concatenated in d_out.
//
// MFMA redesign: one 64-thread block (1 wave) per (b,h).
//  phase1: S = Q^T K via mfma_f32_16x16x32_bf16, M=N=49->64 pad, K=32 exact.
//          hi/lo bf16 split, 3 passes (Qh*Kh + Ql*Kh + Qh*Kl) ~ fp32 accurate.
//  softmax on C-frag layout (col=lane&15, row=(lane>>4)*4+reg, m89-verified)
//          via shfl_xor over 16-lane groups.
//  P staged to 16KB LDS as packed bf16 hi|lo u32, XOR-swizzled (bits 4..5 of s
//          XOR'd with bits 2..3 of t) so frag reads/writes are conflict-light.
//  phase3: score = K P^T, M=32 N=64 K(contraction)=64: 2x4x2 tiles, 3 passes.
//  bias+mask pre-expanded by prep into fragment order -> 32 coalesced f32x4
//          loads per wave instead of per-element gathers.

#define LW 49
#define NH 8

typedef short s16x8 __attribute__((ext_vector_type(8)));
typedef float f32x4 __attribute__((ext_vector_type(4)));

union Frag { s16x8 v; unsigned short u[8]; };

__device__ __forceinline__ unsigned short f2bf(float x) {
    unsigned u = __float_as_uint(x);
    u += 0x7FFFu + ((u >> 16) & 1u);          // round-to-nearest-even
    return (unsigned short)(u >> 16);
}
__device__ __forceinline__ float bf2f(unsigned short h) {
    return __uint_as_float(((unsigned)h) << 16);
}
__device__ __forceinline__ void split8(const float* xf, Frag& hi, Frag& lo) {
    #pragma unroll
    for (int j = 0; j < 8; j++) {
        unsigned short hb = f2bf(xf[j]);
        hi.u[j] = hb;
        lo.u[j] = f2bf(xf[j] - bf2f(hb));
    }
}

#define MFMA16(A, B, C) __builtin_amdgcn_mfma_f32_16x16x32_bf16((A), (B), (C), 0, 0, 0)

// ---------------- prep: bias & mask expanded into C-fragment order ----------
// biasF[h][gi=mt*4+nt][lane][r], maskF[w][gi][lane][r]; value at
// (t = mt*16 + (lane>>4)*4 + r, s = nt*16 + (lane&15)), 0 at pads.
__global__ __launch_bounds__(256) void prep_frag_kernel(
    const float* __restrict__ mask, const float* __restrict__ table,
    const int* __restrict__ idx,
    float* __restrict__ biasF, float* __restrict__ maskF)
{
    const int i = blockIdx.x * 256 + threadIdx.x;
    const int NBF = 8 * 4096;        // 32768
    const int NMF = 64 * 4096;       // 262144
    if (i < NBF) {
        const int h = i >> 12, rem = i & 4095;
        const int gi = rem >> 8, lane = (rem >> 2) & 63, r = rem & 3;
        const int mt = gi >> 2, nt = gi & 3;
        const int t = mt * 16 + (lane >> 4) * 4 + r;
        const int s = nt * 16 + (lane & 15);
        biasF[i] = (t < LW && s < LW) ? table[idx[t * LW + s] * NH + h] : 0.f;
    } else if (i < NBF + NMF) {
        const int j = i - NBF;
        const int w2 = j >> 12, rem = j & 4095;
        const int gi = rem >> 8, lane = (rem >> 2) & 63, r = rem & 3;
        const int mt = gi >> 2, nt = gi & 3;
        const int t = mt * 16 + (lane >> 4) * 4 + r;
        const int s = nt * 16 + (lane & 15);
        maskF[j] = (t < LW && s < LW) ? mask[w2 * (LW * LW) + t * LW + s] : 0.f;
    }
}

// ---------------- main: one wave per (b,h), MFMA both matmuls ---------------
__global__ __launch_bounds__(64, 3) void wa_mfma_kernel(
    const float* __restrict__ q, const float* __restrict__ k,
    const float* __restrict__ biasF, const float* __restrict__ maskF,
    float* __restrict__ score_out, float* __restrict__ attn_out)
{
    __shared__ unsigned sP[64 * 64];      // 16 KiB: P packed bf16 hi|lo

    const int bh   = blockIdx.x;
    const int b    = bh >> 3;
    const int h    = bh & 7;
    const int w    = b & 63;
    const int lane = threadIdx.x;         // 0..63, single wave
    const int l15  = lane & 15;
    const int g4   = lane >> 4;

    const float* qp = q + (size_t)bh * (32 * LW);
    const float* kp = k + (size_t)bh * (32 * LW);

    // ---- A-frags: Q^T rows t, k-run over c; hi/lo split ----
    Frag Qh[4], Ql[4];
    #pragma unroll
    for (int mt = 0; mt < 4; mt++) {
        const int t  = mt * 16 + l15;
        const int tc = t < LW ? t : (LW - 1);          // clamp pad rows
        float xf[8];
        #pragma unroll
        for (int j = 0; j < 8; j++) xf[j] = qp[(g4 * 8 + j) * LW + tc];
        split8(xf, Qh[mt], Ql[mt]);
    }

    // ---- phase 1: S = Q^T K (3-pass split bf16) ----
    f32x4 acc[4][4];
    #pragma unroll
    for (int mt = 0; mt < 4; mt++)
        #pragma unroll
        for (int nt = 0; nt < 4; nt++)
            #pragma unroll
            for (int r = 0; r < 4; r++) acc[mt][nt][r] = 0.f;

    #pragma unroll
    for (int nt = 0; nt < 4; nt++) {
        const int s  = nt * 16 + l15;
        const int sc = s < LW ? s : (LW - 1);
        float xf[8];
        #pragma unroll
        for (int j = 0; j < 8; j++) xf[j] = kp[(g4 * 8 + j) * LW + sc];
        Frag Kh, Kl;
        split8(xf, Kh, Kl);
        #pragma unroll
        for (int mt = 0; mt < 4; mt++) {
            acc[mt][nt] = MFMA16(Qh[mt].v, Kh.v, acc[mt][nt]);
            acc[mt][nt] = MFMA16(Ql[mt].v, Kh.v, acc[mt][nt]);
            acc[mt][nt] = MFMA16(Qh[mt].v, Kl.v, acc[mt][nt]);
        }
    }

    // ---- scale + bias + mask (frag-ordered tables); pad cols -> -inf ----
    const float scale = 0.17677669529663687f;          // 32^-0.5
    const float* bF = biasF + (size_t)h * 4096 + lane * 4;
    const float* mF = maskF + (size_t)w * 4096 + lane * 4;
    #pragma unroll
    for (int mt = 0; mt < 4; mt++) {
        #pragma unroll
        for (int nt = 0; nt < 4; nt++) {
            const int gi = mt * 4 + nt;
            const f32x4 bq = *(const f32x4*)(bF + gi * 256);
            const f32x4 mq = *(const f32x4*)(mF + gi * 256);
            const bool pad = (nt * 16 + l15) >= LW;
            #pragma unroll
            for (int r = 0; r < 4; r++) {
                const float v2 = fmaf(acc[mt][nt][r], scale, bq[r] + mq[r]);
                acc[mt][nt][r] = pad ? -1e30f : v2;
            }
        }
    }

    // ---- softmax over s: row lives on a 16-lane group x 4 nt ----
    float inv[4][4];
    #pragma unroll
    for (int mt = 0; mt < 4; mt++) {
        #pragma unroll
        for (int r = 0; r < 4; r++) {
            float mx = fmaxf(fmaxf(acc[mt][0][r], acc[mt][1][r]),
                             fmaxf(acc[mt][2][r], acc[mt][3][r]));
            mx = fmaxf(mx, __shfl_xor(mx, 1));
            mx = fmaxf(mx, __shfl_xor(mx, 2));
            mx = fmaxf(mx, __shfl_xor(mx, 4));
            mx = fmaxf(mx, __shfl_xor(mx, 8));
            float sm = 0.f;
            #pragma unroll
            for (int nt = 0; nt < 4; nt++) {
                const float p = __expf(acc[mt][nt][r] - mx);
                acc[mt][nt][r] = p;
                sm += p;
            }
            sm += __shfl_xor(sm, 1);
            sm += __shfl_xor(sm, 2);
            sm += __shfl_xor(sm, 4);
            sm += __shfl_xor(sm, 8);
            inv[mt][r] = 1.0f / sm;
        }
    }

    // ---- normalize; write attn; stage P into LDS (bf16 hi|lo packed) ----
    float* attn_base = attn_out + (size_t)bh * (LW * LW);
    #pragma unroll
    for (int mt = 0; mt < 4; mt++) {
        #pragma unroll
        for (int r = 0; r < 4; r++) {
            const int t = mt * 16 + g4 * 4 + r;
            const unsigned swz = (((unsigned)t >> 2) & 3u) << 4;
            #pragma unroll
            for (int nt = 0; nt < 4; nt++) {
                const int s = nt * 16 + l15;
                const float p = acc[mt][nt][r] * inv[mt][r];
                const unsigned short ph = f2bf(p);
                const unsigned short pl = f2bf(p - bf2f(ph));
                sP[t * 64 + (s ^ swz)] = (unsigned)ph | ((unsigned)pl << 16);
                if (t < LW && s < LW) attn_base[t * LW + s] = p;
            }
        }
    }
    // single wave per block: compiler-inserted lgkmcnt orders sP write->read;
    // no s_barrier needed.

    // ---- A-frags for PV: K rows c, k-run over s; hi/lo split ----
    Frag K2h[2][2], K2l[2][2];
    #pragma unroll
    for (int mt = 0; mt < 2; mt++) {
        const int c = mt * 16 + l15;                   // c < 32 always
        #pragma unroll
        for (int ks = 0; ks < 2; ks++) {
            float xf[8];
            #pragma unroll
            for (int j = 0; j < 8; j++) {
                const int s  = ks * 32 + g4 * 8 + j;
                const int sc = s < LW ? s : (LW - 1);  // P at pad s is 0 anyway
                xf[j] = kp[c * LW + sc];
            }
            split8(xf, K2h[mt][ks], K2l[mt][ks]);
        }
    }

    // ---- phase 3: score(c,t) = sum_s K(c,s) P(t,s); 3-pass split ----
    f32x4 acc2[2][4];
    #pragma unroll
    for (int mt = 0; mt < 2; mt++)
        #pragma unroll
        for (int nt = 0; nt < 4; nt++)
            #pragma unroll
            for (int r = 0; r < 4; r++) acc2[mt][nt][r] = 0.f;

    #pragma unroll
    for (int nt = 0; nt < 4; nt++) {
        const int t = nt * 16 + l15;
        const unsigned swz = (((unsigned)t >> 2) & 3u) << 4;
        #pragma unroll
        for (int ks = 0; ks < 2; ks++) {
            const int sb = ks * 32 + g4 * 8;
            const uint4* pp = (const uint4*)&sP[t * 64 + (sb ^ swz)];
            const uint4 a0 = pp[0], a1 = pp[1];
            const unsigned pk[8] = {a0.x, a0.y, a0.z, a0.w,
                                    a1.x, a1.y, a1.z, a1.w};
            Frag Ph, Pl;
            #pragma unroll
            for (int e = 0; e < 8; e++) {
                Ph.u[e] = (unsigned short)(pk[e] & 0xFFFFu);
                Pl.u[e] = (unsigned short)(pk[e] >> 16);
            }
            #pragma unroll
            for (int mt = 0; mt < 2; mt++) {
                acc2[mt][nt] = MFMA16(K2h[mt][ks].v, Ph.v, acc2[mt][nt]);
                acc2[mt][nt] = MFMA16(K2l[mt][ks].v, Ph.v, acc2[mt][nt]);
                acc2[mt][nt] = MFMA16(K2h[mt][ks].v, Pl.v, acc2[mt][nt]);
            }
        }
    }

    // ---- score write: 16-lane contiguous over t -> coalesced ----
    float* sc = score_out + (size_t)bh * (32 * LW);
    #pragma unroll
    for (int mt = 0; mt < 2; mt++) {
        #pragma unroll
        for (int nt = 0; nt < 4; nt++) {
            const int t = nt * 16 + l15;
            if (t < LW) {
                #pragma unroll
                for (int r = 0; r < 4; r++) {
                    const int c = mt * 16 + g4 * 4 + r;
                    sc[c * LW + t] = acc2[mt][nt][r];
                }
            }
        }
    }
}

// ---------------- fallback (ws too small): previous VALU kernel -------------
__global__ __launch_bounds__(256, 4) void wa_fallback_kernel(
    const float* __restrict__ q, const float* __restrict__ k,
    const float* __restrict__ mask0, const float* __restrict__ table,
    const int* __restrict__ idx,
    float* __restrict__ score_out, float* __restrict__ attn_out)
{
    __shared__ float sPf[LW * LW];
    const int lane = threadIdx.x & 63;
    const int wv   = __builtin_amdgcn_readfirstlane(threadIdx.x >> 6);
    const int bh   = blockIdx.x * 4 + wv;
    const int h    = bh & 7;
    const int w    = (bh >> 3) & 63;
    const int t    = lane;
    const int tc   = (t < LW) ? t : (LW - 1);

    const float* qp = q + (size_t)bh * (32 * LW);
    const float* kp = k + (size_t)bh * (32 * LW);

    float qreg[32];
    #pragma unroll
    for (int c = 0; c < 32; c++) qreg[c] = qp[c * LW + tc];

    float S[LW];
    #pragma unroll
    for (int s = 0; s < LW; s++) S[s] = 0.f;
    #pragma unroll
    for (int c = 0; c < 32; c++) {
        #pragma unroll
        for (int s = 0; s < LW; s++)
            S[s] = fmaf(qreg[c], kp[c * LW + s], S[s]);
    }

    const float scale = 0.17677669529663687f;
    const float* mrow = mask0 + (size_t)w * (LW * LW) + tc * LW;
    const int*   irow = idx + tc * LW;
    #pragma unroll
    for (int s = 0; s < LW; s++) {
        const float bm = table[irow[s] * NH + h] + mrow[s];
        S[s] = fmaf(S[s], scale, bm);
    }

    float m = S[0];
    #pragma unroll
    for (int s = 1; s < LW; s++) m = fmaxf(m, S[s]);
    float sum = 0.f;
    #pragma unroll
    for (int s = 0; s < LW; s++) { S[s] = __expf(S[s] - m); sum += S[s]; }
    const float invs = 1.0f / sum;
    #pragma unroll
    for (int s = 0; s < LW; s++) S[s] *= invs;

    float* attn_base = attn_out + (size_t)bh * (LW * LW);
    for (int turn = 0; turn < 4; turn++) {
        __syncthreads();
        if (turn == wv) {
            if (t < LW) {
                #pragma unroll
                for (int s = 0; s < LW; s++) sPf[t * LW + s] = S[s];
            }
            #pragma unroll
            for (int it = 0; it < 38; it++) {
                const int i = it * 64 + lane;
                if (i < LW * LW) attn_base[i] = sPf[i];
            }
        }
    }

    float* sc = score_out + (size_t)bh * (32 * LW);
    #pragma unroll
    for (int c = 0; c < 32; c++) {
        float a = 0.f;
        #pragma unroll
        for (int s = 0; s < LW; s++) a = fmaf(S[s], kp[c * LW + s], a);
        if (t < LW) sc[c * LW + t] = a;
    }
}

extern "C" void kernel_launch(void* const* d_in, const int* in_sizes, int n_in,
                              void* d_out, int out_size, void* d_ws, size_t ws_size,
                              hipStream_t stream) {
    const float* q     = (const float*)d_in[0];
    const float* k     = (const float*)d_in[1];
    // d_in[2] = v, unused: reference reassigns v = k
    const float* mask  = (const float*)d_in[3];
    const float* table = (const float*)d_in[4];
    const int*   idx   = (const int*)d_in[5];

    float* score_out = (float*)d_out;
    float* attn_out  = score_out + (size_t)2048 * 256 * 49;

    const size_t NBF = (size_t)8 * 4096;     // 32768 floats
    const size_t NMF = (size_t)64 * 4096;    // 262144 floats

    if (ws_size >= (NBF + NMF) * sizeof(float)) {
        float* biasF = (float*)d_ws;
        float* maskF = biasF + NBF;
        const int tot = (int)(NBF + NMF);
        prep_frag_kernel<<<(tot + 255) / 256, 256, 0, stream>>>(
            mask, table, idx, biasF, maskF);
        wa_mfma_kernel<<<16384, 64, 0, stream>>>(
            q, k, biasF, maskF, score_out, attn_out);
    } else {
        wa_fallback_kernel<<<4096, 256, 0, stream>>>(
            q, k, mask, table, idx, score_out, attn_out);
    }
}